// Round 15
// baseline (270.220 us; speedup 1.0000x reference)
//
#include <hip/hip_runtime.h>
#include <cstdint>
#include <cstddef>

// Problem dims
#define NB 2
#define NTT 2048
#define ND 1024
#define NK 8
#define NF 4096
#define NTOK (NB*NTT)
#define LAMBDA_C 0.5f

// Output layout (float units)
#define Y_SZ   (NTOK*ND)
#define LG_OFF Y_SZ
#define SC_OFF (LG_OFF + NTOK*NK)
#define AD_OFF (SC_OFF + NK)

// Workspace layout (4-byte units for meta)
#define WS_CNT    0
#define WS_SEG    8
#define WS_NTILES 17
#define WS_TILEK  32
#define WS_TILER  1056
#define WS_PTOK   4096
#define WS_PCOEF  36864
#define WS_COEF   69632
#define WS_X16    102400     // x as f16 (8MB), byte 409600
// byte offsets
#define B_X16   409600ull
#define B_W1T   8798208ull                 // 64MB
#define B_W2T   75907072ull                // 64MB
#define B_HBUFN 143015936ull               // new-path hbuf
#define B_HBUFF 8798208ull                 // fallback hbuf

#define BM 128
#define BN 64
#define BK 64
#define SPLITK2 4
#define KT 16

// fallback LDS offsets
#define AOFF0 0u
#define AOFF1 16384u
#define BOFF0 32768u
#define BOFF1 40960u

typedef float  f32x4 __attribute__((ext_vector_type(4)));
typedef _Float16 f16x8 __attribute__((ext_vector_type(8)));
typedef unsigned int u32x2 __attribute__((ext_vector_type(2)));
typedef unsigned int u32x4 __attribute__((ext_vector_type(4)));

__device__ __forceinline__ unsigned int pkrtz(float a, float b){
    auto h = __builtin_amdgcn_cvt_pkrtz(a, b);
    return __builtin_bit_cast(unsigned int, h);
}
__device__ __forceinline__ float gelu_exact(float v){
    return 0.5f * v * (1.0f + erff(v * 0.70710678118654752440f));
}

// ---------------- x -> f16 prepass ----------------
__global__ __launch_bounds__(256) void k_xcast(const float* __restrict__ x,
                                               unsigned short* __restrict__ x16)
{
    int i = (blockIdx.x*256 + threadIdx.x) * 16;
    const f32x4* src = (const f32x4*)(x + i);
    f32x4 v0 = src[0], v1 = src[1], v2 = src[2], v3 = src[3];
    u32x4 o0 = {pkrtz(v0[0],v0[1]), pkrtz(v0[2],v0[3]), pkrtz(v1[0],v1[1]), pkrtz(v1[2],v1[3])};
    u32x4 o1 = {pkrtz(v2[0],v2[1]), pkrtz(v2[2],v2[3]), pkrtz(v3[0],v3[1]), pkrtz(v3[2],v3[3])};
    *(u32x4*)(x16 + i)     = o0;
    *(u32x4*)(x16 + i + 8) = o1;
}

// ---------------- W transpose-cast prepass v2 (swizzled LDS) ----------------
// LT: 64 rows x 128B. 8B granule g of row r stored at g ^ (2*(r&7)) —
// bijective, preserves 16B pairs (pair p -> p ^ (r&7)) so phase-2 reads b128.
__global__ __launch_bounds__(256) void k_wtrans(
    const float* __restrict__ W1, const float* __restrict__ W2,
    unsigned short* __restrict__ W1T, unsigned short* __restrict__ W2T)
{
    __shared__ char LT[8192];
    int b = blockIdx.x;
    const float* src; unsigned short* dst; int sld, dld;
    if (b < 8192){
        int k = b >> 10, dt = (b >> 6) & 15, ft = b & 63;
        src = W1 + ((size_t)k*ND + dt*64)*NF + ft*64; sld = NF;
        dst = W1T + ((size_t)k*NF + ft*64)*ND + dt*64; dld = ND;
    } else {
        int b2 = b - 8192;
        int k = b2 >> 10, ft = (b2 >> 4) & 63, dt = b2 & 15;
        src = W2 + ((size_t)k*NF + ft*64)*ND + dt*64; sld = ND;
        dst = W2T + ((size_t)k*ND + dt*64)*NF + ft*64; dld = NF;
    }
    int t = threadIdx.x;
    int rg = t >> 4, cg = t & 15;
    f32x4 v[4];
    #pragma unroll
    for (int i = 0; i < 4; i++) v[i] = *(const f32x4*)(src + (size_t)(rg*4+i)*sld + cg*4);
    unsigned wA[4], wB[4];
    #pragma unroll
    for (int r = 0; r < 4; r++){
        wA[r] = pkrtz(v[r][0], v[r][1]);
        wB[r] = pkrtz(v[r][2], v[r][3]);
    }
    #pragma unroll
    for (int j = 0; j < 4; j++){
        unsigned s0 = (j < 2) ? wA[1] : wB[1];
        unsigned s1 = (j < 2) ? wA[0] : wB[0];
        unsigned s2 = (j < 2) ? wA[3] : wB[3];
        unsigned s3 = (j < 2) ? wA[2] : wB[2];
        unsigned sel = (j & 1) ? 0x07060302u : 0x05040100u;
        unsigned o0 = __builtin_amdgcn_perm(s0, s1, sel);
        unsigned o1 = __builtin_amdgcn_perm(s2, s3, sel);
        unsigned row_ = (unsigned)(cg*4 + j);
        unsigned g_ = ((unsigned)rg) ^ (2u*(row_ & 7u));
        *(u32x2*)(&LT[row_*128u + g_*8u]) = (u32x2){o0, o1};
    }
    __syncthreads();
    int c = t >> 2, ch = t & 3;
    unsigned sfx = (unsigned)c & 7u;
    unsigned p0 = ((unsigned)(2*ch))     ^ sfx;
    unsigned p1 = ((unsigned)(2*ch + 1)) ^ sfx;
    u32x4 r0 = *(const u32x4*)(&LT[(unsigned)c*128u + p0*16u]);
    u32x4 r1 = *(const u32x4*)(&LT[(unsigned)c*128u + p1*16u]);
    unsigned short* dp = dst + (size_t)c*dld + ch*16;
    *(u32x4*)(dp)     = r0;
    *(u32x4*)(dp + 8) = r1;
}

// ---------------- gating ----------------
__global__ __launch_bounds__(256) void k_gating(
    const float* __restrict__ x, const float* __restrict__ pl,
    const float* __restrict__ Wt, const float* __restrict__ Wgt,
    const float* __restrict__ Wel, float* __restrict__ out,
    float* __restrict__ coef, int* __restrict__ cnt)
{
    int t = blockIdx.x;
    const float* xt = x + (size_t)t * ND;
    float acc[NK] = {0,0,0,0,0,0,0,0};
    for (int d = threadIdx.x; d < ND; d += 256){
        float xv = xt[d];
        const float4* w = (const float4*)(Wt + (size_t)d * NK);
        float4 w0 = w[0], w1 = w[1];
        acc[0] += xv*w0.x; acc[1] += xv*w0.y; acc[2] += xv*w0.z; acc[3] += xv*w0.w;
        acc[4] += xv*w1.x; acc[5] += xv*w1.y; acc[6] += xv*w1.z; acc[7] += xv*w1.w;
    }
    __shared__ float red[4][NK];
    #pragma unroll
    for (int k = 0; k < NK; k++){
        float v = acc[k];
        #pragma unroll
        for (int off = 32; off; off >>= 1) v += __shfl_down(v, off);
        if ((threadIdx.x & 63) == 0) red[threadIdx.x >> 6][k] = v;
    }
    __syncthreads();
    if (threadIdx.x == 0){
        const float* p = pl + (size_t)t * NK;
        float pv[NK];
        #pragma unroll
        for (int j = 0; j < NK; j++) pv[j] = p[j];
        float lg[NK]; float mx = -1e30f;
        #pragma unroll
        for (int k = 0; k < NK; k++){
            float v = red[0][k] + red[1][k] + red[2][k] + red[3][k];
            #pragma unroll
            for (int j = 0; j < NK; j++) v += pv[j] * Wgt[j*NK + k];
            lg[k] = v; mx = fmaxf(mx, v);
            out[LG_OFF + (size_t)t*NK + k] = v;
        }
        float e[NK]; float s = 0.f;
        #pragma unroll
        for (int k = 0; k < NK; k++){ e[k] = expf(lg[k] - mx); s += e[k]; }
        float g[NK]; float gsum = 0.f;
        #pragma unroll
        for (int k = 0; k < NK; k++){
            float st = e[k] / s;
            float we = 1.f / (1.f + expf(-Wel[k]));
            bool m = st > LAMBDA_C * we;
            g[k] = m ? st : 0.f;
            gsum += g[k];
        }
        float inv = 1.f / (gsum + 1e-6f);
        #pragma unroll
        for (int k = 0; k < NK; k++){
            coef[(size_t)t*NK + k] = g[k] * inv;
            if (g[k] > 0.f) atomicAdd(&cnt[k], 1);
        }
    }
}

// ---------------- scan ----------------
__global__ __launch_bounds__(256) void k_scan(
    const float* __restrict__ coef, int* __restrict__ wsi,
    float* __restrict__ wsf, int pair_cap)
{
    int k = blockIdx.x;
    const int* cnt = wsi + WS_CNT;
    int base = 0;
    for (int j = 0; j < k; j++) base += cnt[j];
    int tid = threadIdx.x, lane = tid & 63, w = tid >> 6;
    __shared__ int wsum[4];
    __shared__ int sbase;
    if (tid == 0){
        sbase = base;
        wsi[WS_SEG + k] = base;
        if (k == NK-1) wsi[WS_SEG + NK] = base + cnt[k];
    }
    __syncthreads();
    int* ptok = wsi + WS_PTOK;
    float* pc = wsf + WS_PCOEF;
    for (int c0 = 0; c0 < NTOK; c0 += 256){
        int t = c0 + tid;
        float c = coef[(size_t)t*NK + k];
        bool m = c > 0.f;
        unsigned long long bal = __ballot(m);
        int pre = __popcll(bal & ((1ull << lane) - 1ull));
        if (lane == 0) wsum[w] = __popcll(bal);
        __syncthreads();
        int b = sbase;
        for (int j = 0; j < w; j++) b += wsum[j];
        if (m){
            int pos = b + pre;
            if (pos < pair_cap){ ptok[pos] = t; pc[pos] = c; }
        }
        __syncthreads();
        if (tid == 0) sbase += wsum[0] + wsum[1] + wsum[2] + wsum[3];
        __syncthreads();
    }
}

// ---------------- tiles + small outputs ----------------
__global__ void k_tiles(int* __restrict__ wsi, float* __restrict__ out, int pair_cap)
{
    if (threadIdx.x == 0 && blockIdx.x == 0){
        const int* cnt = wsi + WS_CNT;
        const int* seg = wsi + WS_SEG;
        int total = 0;
        for (int k = 0; k < NK; k++){ total += cnt[k]; out[SC_OFF + k] = (float)cnt[k]; }
        out[AD_OFF] = (float)total / (float)NTOK;
        int nt = 0;
        for (int k = 0; k < NK; k++){
            int e = min(seg[k+1], pair_cap);
            for (int r = seg[k]; r < e; r += BM){
                wsi[WS_TILEK + nt] = k; wsi[WS_TILER + nt] = r; nt++;
            }
        }
        wsi[WS_NTILES] = nt;
    }
}

// XCD-chunked bijective work partition
#define XCD_PART_LOOP(nwork)                                              \
    int q_ = (nwork) >> 3, rr_ = (nwork) & 7;                             \
    int xcd_ = blockIdx.x & 7;                                            \
    int slot_ = blockIdx.x >> 3;                                          \
    int nslot_ = gridDim.x >> 3;                                          \
    int cntw_ = q_ + (xcd_ < rr_ ? 1 : 0);                                \
    int start_ = xcd_ * q_ + (xcd_ < rr_ ? xcd_ : rr_);                   \
    for (int p_ = slot_; p_ < cntw_; p_ += nslot_)

// ============== NEW-PATH m97-style GEMMs, 3-slot depth-2 GLL pipeline ==============
// Slot (16KB): A 8KB + B 8KB. 128 rows x 64B; row r, 16B slot s holds k-quad s^(r&3).
// gll linear dest; per-lane source pre-swizzled (m173). frag read conflict-free.

#define GLLN(aP0_, aP1_, bP0_, bP1_, t_, slot_)                           \
  { unsigned ab_ = (unsigned)(slot_)*16384u + (unsigned)(wv*1024);        \
    __builtin_amdgcn_global_load_lds(                                     \
        (const __attribute__((address_space(1))) void*)((aP0_) + (size_t)(t_)*32), \
        (__attribute__((address_space(3))) void*)(&lds[ab_]), 16, 0, 0);  \
    __builtin_amdgcn_global_load_lds(                                     \
        (const __attribute__((address_space(1))) void*)((aP1_) + (size_t)(t_)*32), \
        (__attribute__((address_space(3))) void*)(&lds[ab_ + 4096u]), 16, 0, 0); \
    __builtin_amdgcn_global_load_lds(                                     \
        (const __attribute__((address_space(1))) void*)((bP0_) + (size_t)(t_)*32), \
        (__attribute__((address_space(3))) void*)(&lds[ab_ + 8192u]), 16, 0, 0); \
    __builtin_amdgcn_global_load_lds(                                     \
        (const __attribute__((address_space(1))) void*)((bP1_) + (size_t)(t_)*32), \
        (__attribute__((address_space(3))) void*)(&lds[ab_ + 12288u]), 16, 0, 0); }

#define MFMAN(slot_)                                                      \
  { unsigned ab_ = (unsigned)(slot_)*16384u, bb_ = ab_ + 8192u;           \
    f16x8 af_[4], bf_[4];                                                 \
    _Pragma("unroll")                                                     \
    for (int m_ = 0; m_ < 4; m_++) af_[m_] = *(const f16x8*)(&lds[ab_ + aoff[m_]]); \
    _Pragma("unroll")                                                     \
    for (int n_ = 0; n_ < 4; n_++) bf_[n_] = *(const f16x8*)(&lds[bb_ + boff[n_]]); \
    __builtin_amdgcn_s_setprio(1);                                        \
    _Pragma("unroll")                                                     \
    for (int m_ = 0; m_ < 4; m_++)                                        \
    _Pragma("unroll")                                                     \
    for (int n_ = 0; n_ < 4; n_++)                                        \
        acc[m_][n_] = __builtin_amdgcn_mfma_f32_16x16x32_f16(af_[m_], bf_[n_], acc[m_][n_], 0, 0, 0); \
    __builtin_amdgcn_s_setprio(0); }

// Steady state at the vmcnt: outstanding = GLL(t+1)[4] + GLL(t+2)[4] = 8;
// vmcnt(4) drains exactly GLL(t+1); GLL(t+2) rides across the barrier (T4).
#define PIPE_N(APREF0_, APREF1_, BPREF0_, BPREF1_)                        \
    GLLN(APREF0_, APREF1_, BPREF0_, BPREF1_, 0, 0)                        \
    GLLN(APREF0_, APREF1_, BPREF0_, BPREF1_, 1, 1)                        \
    asm volatile("s_waitcnt vmcnt(4)" ::: "memory");                      \
    __builtin_amdgcn_s_barrier();                                         \
    __builtin_amdgcn_sched_barrier(0);                                    \
    for (int t = 0; t < 32; t++){                                         \
        int sl = t % 3;                                                   \
        if (t + 2 < 32){                                                  \
            GLLN(APREF0_, APREF1_, BPREF0_, BPREF1_, t+2, (t+2)%3)        \
            MFMAN(sl)                                                     \
            asm volatile("s_waitcnt vmcnt(4)" ::: "memory");              \
            __builtin_amdgcn_s_barrier();                                 \
            __builtin_amdgcn_sched_barrier(0);                            \
        } else if (t + 1 < 32){                                           \
            MFMAN(sl)                                                     \
            asm volatile("s_waitcnt vmcnt(0)" ::: "memory");              \
            __builtin_amdgcn_s_barrier();                                 \
            __builtin_amdgcn_sched_barrier(0);                            \
        } else {                                                          \
            MFMAN(sl)                                                     \
        }                                                                 \
    }

#define GEMMN_PRE()                                                       \
    int tid = threadIdx.x;                                                \
    int L = tid & 63;                                                     \
    int wv = tid >> 6;                                                    \
    int wr = wv >> 1, wc = wv & 1;                                        \
    int l15 = L & 15, q = L >> 4;                                         \
    unsigned aoff[4], boff[4];                                            \
    _Pragma("unroll")                                                     \
    for (int m_ = 0; m_ < 4; m_++){                                       \
        int r_ = wr*64 + m_*16 + l15;                                     \
        aoff[m_] = (unsigned)(r_*64) + ((unsigned)((q ^ r_) & 3) << 4);   \
    }                                                                     \
    _Pragma("unroll")                                                     \
    for (int n_ = 0; n_ < 4; n_++){                                       \
        int c_ = wc*64 + n_*16 + l15;                                     \
        boff[n_] = (unsigned)(c_*64) + ((unsigned)((q ^ c_) & 3) << 4);   \
    }                                                                     \
    int grow0 = wv*16 + (L >> 2);                                         \
    int grow1 = (4 + wv)*16 + (L >> 2);                                   \
    int qg8 = (((L & 3) ^ ((L >> 2) & 3))) * 8;

__global__ __launch_bounds__(256, 3) void k_gemm1n(
    const unsigned short* __restrict__ x16, const unsigned short* __restrict__ w1t,
    const float* __restrict__ b1, const int* __restrict__ wsi,
    unsigned short* __restrict__ hbuf, int pair_cap)
{
    __shared__ char lds[49152];
    __shared__ int stok[BM];
    const int* seg  = wsi + WS_SEG;
    const int* tk   = wsi + WS_TILEK;
    const int* tr   = wsi + WS_TILER;
    const int* ptok = wsi + WS_PTOK;
    int ntm = wsi[WS_NTILES];
    int nwork = ntm * (NF / 128);
    GEMMN_PRE()

    XCD_PART_LOOP(nwork){
        int widx = start_ + p_;
        int mt = widx % ntm;
        int ft = widx / ntm;
        int kexp = tk[mt];
        int row0 = tr[mt];
        int nrows = min(BM, seg[kexp+1] - row0);
        int f0 = ft * 128;
        __syncthreads();
        if (tid < BM){
            int r = row0 + tid;
            stok[tid] = (tid < nrows && r < pair_cap) ? ptok[r] : ptok[row0];
        }
        __syncthreads();
        const unsigned short* a0 = x16 + (size_t)stok[grow0]*ND + qg8;
        const unsigned short* a1 = x16 + (size_t)stok[grow1]*ND + qg8;
        const unsigned short* bb = w1t + (size_t)kexp*NF*ND;
        const unsigned short* b0 = bb + (size_t)(f0 + grow0)*ND + qg8;
        const unsigned short* b1p = bb + (size_t)(f0 + grow1)*ND + qg8;
        f32x4 acc[4][4] = {};
        PIPE_N(a0, a1, b0, b1p)
        const float* b1k = b1 + (size_t)kexp*NF;
        #pragma unroll
        for (int n = 0; n < 4; n++){
            int f = f0 + wc*64 + n*16 + l15;
            float bv = b1k[f];
            #pragma unroll
            for (int m = 0; m < 4; m++){
                int rl = wr*64 + m*16 + q*4;
                #pragma unroll
                for (int i = 0; i < 4; i++){
                    int r = rl + i;
                    if (r < nrows && row0 + r < pair_cap){
                        float v = gelu_exact(acc[m][n][i] + bv);
                        hbuf[(size_t)(row0+r)*NF + f] = (unsigned short)(pkrtz(v, 0.f) & 0xffffu);
                    }
                }
            }
        }
    }
}

__global__ __launch_bounds__(256, 3) void k_gemm2n(
    const unsigned short* __restrict__ hbuf, const unsigned short* __restrict__ w2t,
    const float* __restrict__ b2, const int* __restrict__ wsi,
    const float* __restrict__ wsf, float* __restrict__ out, int pair_cap)
{
    __shared__ char lds[49152];
    __shared__ int stok[BM];
    __shared__ float scoef[BM];
    const int* seg  = wsi + WS_SEG;
    const int* tk   = wsi + WS_TILEK;
    const int* tr   = wsi + WS_TILER;
    const int* ptok = wsi + WS_PTOK;
    const float* pcoef = wsf + WS_PCOEF;
    int ntm = wsi[WS_NTILES];
    int nwork = ntm * (ND / 128) * SPLITK2;
    GEMMN_PRE()

    XCD_PART_LOOP(nwork){
        int widx = start_ + p_;
        int mt = widx % ntm;
        int rest = widx / ntm;
        int dt = rest & 7;
        int spk = rest >> 3;
        int kexp = tk[mt];
        int row0 = tr[mt];
        int nrows = min(BM, seg[kexp+1] - row0);
        int d0 = dt * 128;
        __syncthreads();
        if (tid < BM){
            int r = row0 + tid;
            bool v = (tid < nrows && r < pair_cap);
            stok[tid]  = v ? ptok[r] : 0;
            scoef[tid] = v ? pcoef[r] : 0.f;
        }
        __syncthreads();
        int ar0 = row0 + grow0; if (ar0 >= pair_cap) ar0 = pair_cap - 1;
        int ar1 = row0 + grow1; if (ar1 >= pair_cap) ar1 = pair_cap - 1;
        const unsigned short* a0 = hbuf + (size_t)ar0*NF + spk*(NF/SPLITK2) + qg8;
        const unsigned short* a1 = hbuf + (size_t)ar1*NF + spk*(NF/SPLITK2) + qg8;
        const unsigned short* bb = w2t + (size_t)kexp*ND*NF + spk*(NF/SPLITK2);
        const unsigned short* b0 = bb + (size_t)(d0 + grow0)*NF + qg8;
        const unsigned short* b1p = bb + (size_t)(d0 + grow1)*NF + qg8;
        f32x4 acc[4][4] = {};
        PIPE_N(a0, a1, b0, b1p)
        const float* b2k = b2 + (size_t)kexp*ND;
        #pragma unroll
        for (int n = 0; n < 4; n++){
            int d = d0 + wc*64 + n*16 + l15;
            float bv = (spk == 0) ? b2k[d] : 0.f;
            #pragma unroll
            for (int m = 0; m < 4; m++){
                int rl = wr*64 + m*16 + q*4;
                #pragma unroll
                for (int i = 0; i < 4; i++){
                    int r = rl + i;
                    if (r < nrows && row0 + r < pair_cap){
                        float c = scoef[r];
                        atomicAdd(&out[(size_t)stok[r]*ND + d], c * (acc[m][n][i] + bv));
                    }
                }
            }
        }
    }
}

// ============== FALLBACK (R13) GEMMs — used when ws is small ==============
#define LOAD_A(dst_, tt_)                                                 \
    { const unsigned short* an_ = asrc + (tt_)*BK;                        \
      _Pragma("unroll")                                                   \
      for (int j_ = 0; j_ < 4; j_++) dst_[j_] = *(const u32x4*)(an_ + j_*8); }

#define LOAD_B(dst_, tt_, LDW_)                                           \
    { const float* bn_ = bsrc + (size_t)((tt_)*BK + bkq*4)*LDW_;          \
      _Pragma("unroll")                                                   \
      for (int r_ = 0; r_ < 4; r_++) dst_[r_] = *(const f32x4*)(bn_ + (size_t)r_*LDW_); }

#define STAGE_A(src_, AO_)                                                \
    { _Pragma("unroll")                                                   \
      for (int j_ = 0; j_ < 4; j_++){                                     \
          unsigned off_ = (AO_) + (unsigned)arow*128u +                   \
              ((((unsigned)(ahalf*4 + j_)) ^ (unsigned)(arow & 7)) << 4); \
          *(u32x4*)(&lds[off_]) = src_[j_];                               \
      } }

#define STAGE_B(src_, BO_)                                                \
    { unsigned wA_[4], wB_[4];                                            \
      _Pragma("unroll")                                                   \
      for (int r_ = 0; r_ < 4; r_++){                                     \
          wA_[r_] = pkrtz(src_[r_][0], src_[r_][1]);                      \
          wB_[r_] = pkrtz(src_[r_][2], src_[r_][3]);                      \
      }                                                                   \
      _Pragma("unroll")                                                   \
      for (int j_ = 0; j_ < 4; j_++){                                     \
          unsigned s0_ = (j_ < 2) ? wA_[1] : wB_[1];                      \
          unsigned s1_ = (j_ < 2) ? wA_[0] : wB_[0];                      \
          unsigned s2_ = (j_ < 2) ? wA_[3] : wB_[3];                      \
          unsigned s3_ = (j_ < 2) ? wA_[2] : wB_[2];                      \
          unsigned sel_ = (j_ & 1) ? 0x07060302u : 0x05040100u;           \
          unsigned o0_ = __builtin_amdgcn_perm(s0_, s1_, sel_);           \
          unsigned o1_ = __builtin_amdgcn_perm(s2_, s3_, sel_);           \
          unsigned col_ = (unsigned)(bcc*4 + j_);                         \
          unsigned off_ = (BO_) + col_*128u +                             \
              (((unsigned)(bkq*8)) ^ ((col_ & 7u) << 4));                 \
          *(u32x2*)(&lds[off_]) = (u32x2){o0_, o1_};                      \
      } }

#define MFMA_RD(AO_, BO_)                                                 \
    { __builtin_amdgcn_s_setprio(1);                                      \
      _Pragma("unroll")                                                   \
      for (int kk_ = 0; kk_ < 2; kk_++){                                  \
          unsigned sb_ = ((unsigned)(kk_*64 + q*16)) ^ swzL;              \
          f16x8 af_[4], bf_[2];                                           \
          _Pragma("unroll")                                               \
          for (int m_ = 0; m_ < 4; m_++)                                  \
              af_[m_] = *(const f16x8*)(&lds[(AO_) + (unsigned)(wr*64 + m_*16 + l15)*128u + sb_]); \
          _Pragma("unroll")                                               \
          for (int n_ = 0; n_ < 2; n_++)                                  \
              bf_[n_] = *(const f16x8*)(&lds[(BO_) + (unsigned)(wc*32 + n_*16 + l15)*128u + sb_]); \
          _Pragma("unroll")                                               \
          for (int m_ = 0; m_ < 4; m_++)                                  \
          _Pragma("unroll")                                               \
          for (int n_ = 0; n_ < 2; n_++)                                  \
              acc[m_][n_] = __builtin_amdgcn_mfma_f32_16x16x32_f16(af_[m_], bf_[n_], acc[m_][n_], 0, 0, 0); \
      }                                                                   \
      __builtin_amdgcn_s_setprio(0); }

#define STEP_SYNC()                                                       \
    asm volatile("s_waitcnt lgkmcnt(0)" ::: "memory");                    \
    __builtin_amdgcn_s_barrier();                                         \
    __builtin_amdgcn_sched_barrier(0);

__global__ __launch_bounds__(256, 3) void k_gemm1f(
    const unsigned short* __restrict__ x16, const float* __restrict__ W1,
    const float* __restrict__ b1, const int* __restrict__ wsi,
    unsigned short* __restrict__ hbuf, int pair_cap)
{
    __shared__ char lds[49152];
    __shared__ int stok[BM];
    const int* seg  = wsi + WS_SEG;
    const int* tk   = wsi + WS_TILEK;
    const int* tr   = wsi + WS_TILER;
    const int* ptok = wsi + WS_PTOK;
    int ntm = wsi[WS_NTILES];
    int nwork = ntm * (NF / BN);
    int tid  = threadIdx.x;
    int lane = tid & 63;
    int w    = tid >> 6;
    int wr = w >> 1, wc = w & 1;
    int l15 = lane & 15, q = lane >> 4;
    unsigned swzL = (unsigned)((l15 & 7) << 4);
    int arow = tid >> 1, ahalf = tid & 1;
    int bkq = tid >> 4, bcc = tid & 15;

    XCD_PART_LOOP(nwork){
        int widx = start_ + p_;
        int mt = widx % ntm;
        int ft = widx / ntm;
        int kexp = tk[mt];
        int row0 = tr[mt];
        int nrows = min(BM, seg[kexp+1] - row0);
        int f0 = ft * BN;
        __syncthreads();
        if (tid < BM){
            int r = row0 + tid;
            stok[tid] = (tid < nrows && r < pair_cap) ? ptok[r] : ptok[row0];
        }
        __syncthreads();
        const unsigned short* asrc = x16 + (size_t)stok[arow]*ND + ahalf*32;
        const float* bsrc = W1 + (size_t)kexp*ND*NF + f0 + bcc*4;
        u32x4 ga0[4], ga1[4]; f32x4 gb0[4], gb1[4];
        LOAD_A(ga0, 0) LOAD_B(gb0, 0, NF)
        LOAD_A(ga1, 1) LOAD_B(gb1, 1, NF)
        f32x4 acc[4][2] = {};
        for (int t = 0; t < KT; t += 2){
            STAGE_A(ga0, AOFF0) STAGE_B(gb0, BOFF0)
            if (t + 2 < KT){ LOAD_A(ga0, t+2) LOAD_B(gb0, t+2, NF) }
            STEP_SYNC()
            MFMA_RD(AOFF0, BOFF0)
            STAGE_A(ga1, AOFF1) STAGE_B(gb1, BOFF1)
            if (t + 3 < KT){ LOAD_A(ga1, t+3) LOAD_B(gb1, t+3, NF) }
            STEP_SYNC()
            MFMA_RD(AOFF1, BOFF1)
        }
        const float* b1k = b1 + (size_t)kexp*NF;
        #pragma unroll
        for (int n = 0; n < 2; n++){
            int f = f0 + wc*32 + n*16 + l15;
            float bv = b1k[f];
            #pragma unroll
            for (int m = 0; m < 4; m++){
                int rl = wr*64 + m*16 + q*4;
                #pragma unroll
                for (int i = 0; i < 4; i++){
                    int r = rl + i;
                    if (r < nrows && row0 + r < pair_cap){
                        float v = gelu_exact(acc[m][n][i] + bv);
                        hbuf[(size_t)(row0+r)*NF + f] = (unsigned short)(pkrtz(v, 0.f) & 0xffffu);
                    }
                }
            }
        }
    }
}

__global__ __launch_bounds__(256, 3) void k_gemm2f(
    const unsigned short* __restrict__ hbuf, const float* __restrict__ W2,
    const float* __restrict__ b2, const int* __restrict__ wsi,
    const float* __restrict__ wsf, float* __restrict__ out, int pair_cap)
{
    __shared__ char lds[49152];
    __shared__ int stok[BM];
    __shared__ float scoef[BM];
    const int* seg  = wsi + WS_SEG;
    const int* tk   = wsi + WS_TILEK;
    const int* tr   = wsi + WS_TILER;
    const int* ptok = wsi + WS_PTOK;
    const float* pcoef = wsf + WS_PCOEF;
    int ntm = wsi[WS_NTILES];
    int nwork = ntm * (ND / BN) * SPLITK2;
    int tid  = threadIdx.x;
    int lane = tid & 63;
    int w    = tid >> 6;
    int wr = w >> 1, wc = w & 1;
    int l15 = lane & 15, q = lane >> 4;
    unsigned swzL = (unsigned)((l15 & 7) << 4);
    int arow = tid >> 1, ahalf = tid & 1;
    int bkq = tid >> 4, bcc = tid & 15;

    XCD_PART_LOOP(nwork){
        int widx = start_ + p_;
        int mt = widx % ntm;
        int rest = widx / ntm;
        int dt = rest & 15;
        int sp = rest >> 4;
        int kexp = tk[mt];
        int row0 = tr[mt];
        int nrows = min(BM, seg[kexp+1] - row0);
        int d0 = dt * BN;
        __syncthreads();
        if (tid < BM){
            int r = row0 + tid;
            bool v = (tid < nrows && r < pair_cap);
            stok[tid]  = v ? ptok[r] : 0;
            scoef[tid] = v ? pcoef[r] : 0.f;
        }
        __syncthreads();
        int hr = row0 + arow; if (hr >= pair_cap) hr = pair_cap - 1;
        const unsigned short* asrc = hbuf + (size_t)hr*NF + sp*(NF/SPLITK2) + ahalf*32;
        const float* bsrc = W2 + (size_t)kexp*NF*ND + (size_t)sp*(NF/SPLITK2)*ND + d0 + bcc*4;
        u32x4 ga0[4], ga1[4]; f32x4 gb0[4], gb1[4];
        LOAD_A(ga0, 0) LOAD_B(gb0, 0, ND)
        LOAD_A(ga1, 1) LOAD_B(gb1, 1, ND)
        f32x4 acc[4][2] = {};
        for (int t = 0; t < KT; t += 2){
            STAGE_A(ga0, AOFF0) STAGE_B(gb0, BOFF0)
            if (t + 2 < KT){ LOAD_A(ga0, t+2) LOAD_B(gb0, t+2, ND) }
            STEP_SYNC()
            MFMA_RD(AOFF0, BOFF0)
            STAGE_A(ga1, AOFF1) STAGE_B(gb1, BOFF1)
            if (t + 3 < KT){ LOAD_A(ga1, t+3) LOAD_B(gb1, t+3, ND) }
            STEP_SYNC()
            MFMA_RD(AOFF1, BOFF1)
        }
        const float* b2k = b2 + (size_t)kexp*ND;
        #pragma unroll
        for (int n = 0; n < 2; n++){
            int d = d0 + wc*32 + n*16 + l15;
            float bv = (sp == 0) ? b2k[d] : 0.f;
            #pragma unroll
            for (int m = 0; m < 4; m++){
                int rl = wr*64 + m*16 + q*4;
                #pragma unroll
                for (int i = 0; i < 4; i++){
                    int r = rl + i;
                    if (r < nrows && row0 + r < pair_cap){
                        float c = scoef[r];
                        atomicAdd(&out[(size_t)stok[r]*ND + d], c * (acc[m][n][i] + bv));
                    }
                }
            }
        }
    }
}

extern "C" void kernel_launch(void* const* d_in, const int* in_sizes, int n_in,
                              void* d_out, int out_size, void* d_ws, size_t ws_size,
                              hipStream_t stream)
{
    const float* x   = (const float*)d_in[0];
    const float* pl  = (const float*)d_in[1];
    const float* Wt  = (const float*)d_in[2];
    const float* Wgt = (const float*)d_in[3];
    const float* Wel = (const float*)d_in[4];
    const float* W1  = (const float*)d_in[5];
    const float* b1  = (const float*)d_in[6];
    const float* W2  = (const float*)d_in[7];
    const float* b2  = (const float*)d_in[8];
    float* out = (float*)d_out;
    int* wsi   = (int*)d_ws;
    float* wsf = (float*)d_ws;
    unsigned short* x16 = (unsigned short*)((char*)d_ws + B_X16);

    long long capn = ((long long)ws_size - (long long)B_HBUFN) / ((long long)NF*2);
    bool newpath = capn >= 4096;

    hipMemsetAsync(d_out, 0, (size_t)out_size*sizeof(float), stream);
    hipMemsetAsync(d_ws, 0, 32, stream);   // cnt[8]
    k_xcast<<<1024, 256, 0, stream>>>(x, x16);
    k_gating<<<NTOK, 256, 0, stream>>>(x, pl, Wt, Wgt, Wel, out, wsf + WS_COEF, wsi + WS_CNT);

    if (newpath){
        unsigned short* w1t  = (unsigned short*)((char*)d_ws + B_W1T);
        unsigned short* w2t  = (unsigned short*)((char*)d_ws + B_W2T);
        unsigned short* hbuf = (unsigned short*)((char*)d_ws + B_HBUFN);
        int pair_cap = (int)((capn > 32768) ? 32768 : capn);
        k_wtrans<<<16384, 256, 0, stream>>>(W1, W2, w1t, w2t);
        k_scan<<<NK, 256, 0, stream>>>(wsf + WS_COEF, wsi, wsf, pair_cap);
        k_tiles<<<1, 64, 0, stream>>>(wsi, out, pair_cap);
        k_gemm1n<<<2048, 256, 0, stream>>>(x16, w1t, b1, wsi, hbuf, pair_cap);
        k_gemm2n<<<2048, 256, 0, stream>>>(hbuf, w2t, b2, wsi, wsf, out, pair_cap);
    } else {
        unsigned short* hbuf = (unsigned short*)((char*)d_ws + B_HBUFF);
        long long cap = ((long long)ws_size - (long long)B_HBUFF) / ((long long)NF*2);
        if (cap > (long long)NTOK*NK) cap = (long long)NTOK*NK;
        if (cap < 0) cap = 0;
        int pair_cap = (int)cap;
        if (pair_cap > 0){
            k_scan<<<NK, 256, 0, stream>>>(wsf + WS_COEF, wsi, wsf, pair_cap);
            k_tiles<<<1, 64, 0, stream>>>(wsi, out, pair_cap);
            k_gemm1f<<<2048, 256, 0, stream>>>(x16, W1, b1, wsi, hbuf, pair_cap);
            k_gemm2f<<<2048, 256, 0, stream>>>(hbuf, W2, b2, wsi, wsf, out, pair_cap);
        }
    }
}

// Round 16
// 261.316 us; speedup vs baseline: 1.0341x; 1.0341x over previous
//
#include <hip/hip_runtime.h>
#include <cstdint>
#include <cstddef>

// Problem dims
#define NB 2
#define NTT 2048
#define ND 1024
#define NK 8
#define NF 4096
#define NTOK (NB*NTT)
#define LAMBDA_C 0.5f

// Output layout (float units)
#define Y_SZ   (NTOK*ND)
#define LG_OFF Y_SZ
#define SC_OFF (LG_OFF + NTOK*NK)
#define AD_OFF (SC_OFF + NK)

// Workspace layout (4-byte units for meta)
#define WS_CNT    0
#define WS_SEG    8
#define WS_NTILES 17
#define WS_TILEK  32
#define WS_TILER  1056
#define WS_PTOK   4096
#define WS_PCOEF  36864
#define WS_COEF   69632
#define WS_X16    102400
// byte offsets
#define B_X16   409600ull
#define B_W1T   8798208ull
#define B_W2T   75907072ull
#define B_HBUFN 143015936ull
#define B_HBUFF 8798208ull

#define BM 128
#define BN 64
#define BK 64
#define SPLITK2 4
#define KT 16

// fallback LDS offsets
#define AOFF0 0u
#define AOFF1 16384u
#define BOFF0 32768u
#define BOFF1 40960u

typedef float  f32x4 __attribute__((ext_vector_type(4)));
typedef _Float16 f16x8 __attribute__((ext_vector_type(8)));
typedef unsigned int u32x2 __attribute__((ext_vector_type(2)));
typedef unsigned int u32x4 __attribute__((ext_vector_type(4)));

__device__ __forceinline__ unsigned int pkrtz(float a, float b){
    auto h = __builtin_amdgcn_cvt_pkrtz(a, b);
    return __builtin_bit_cast(unsigned int, h);
}
__device__ __forceinline__ float gelu_exact(float v){
    return 0.5f * v * (1.0f + erff(v * 0.70710678118654752440f));
}

// ---------------- W transpose-cast prepass v3 (row>>2-keyed swizzle) ----------------
// LT: 64 rows x 128B. 8B granule g of row r at g ^ (((r>>2)&3)<<2):
// write phase spreads a wave over all 16 granule slots; read phase (16B blocks,
// p' = p ^ (((r>>2)&3)<<1)) spreads over all 8 block positions. Both at floor.
__global__ __launch_bounds__(256) void k_wtrans(
    const float* __restrict__ W1, const float* __restrict__ W2,
    unsigned short* __restrict__ W1T, unsigned short* __restrict__ W2T)
{
    __shared__ char LT[8192];
    int b = blockIdx.x;
    const float* src; unsigned short* dst; int sld, dld;
    if (b < 8192){
        int k = b >> 10, dt = (b >> 6) & 15, ft = b & 63;
        src = W1 + ((size_t)k*ND + dt*64)*NF + ft*64; sld = NF;
        dst = W1T + ((size_t)k*NF + ft*64)*ND + dt*64; dld = ND;
    } else {
        int b2 = b - 8192;
        int k = b2 >> 10, ft = (b2 >> 4) & 63, dt = b2 & 15;
        src = W2 + ((size_t)k*NF + ft*64)*ND + dt*64; sld = ND;
        dst = W2T + ((size_t)k*ND + dt*64)*NF + ft*64; dld = NF;
    }
    int t = threadIdx.x;
    int rg = t >> 4, cg = t & 15;
    f32x4 v[4];
    #pragma unroll
    for (int i = 0; i < 4; i++) v[i] = *(const f32x4*)(src + (size_t)(rg*4+i)*sld + cg*4);
    unsigned wA[4], wB[4];
    #pragma unroll
    for (int r = 0; r < 4; r++){
        wA[r] = pkrtz(v[r][0], v[r][1]);
        wB[r] = pkrtz(v[r][2], v[r][3]);
    }
    #pragma unroll
    for (int j = 0; j < 4; j++){
        unsigned s0 = (j < 2) ? wA[1] : wB[1];
        unsigned s1 = (j < 2) ? wA[0] : wB[0];
        unsigned s2 = (j < 2) ? wA[3] : wB[3];
        unsigned s3 = (j < 2) ? wA[2] : wB[2];
        unsigned sel = (j & 1) ? 0x07060302u : 0x05040100u;
        unsigned o0 = __builtin_amdgcn_perm(s0, s1, sel);
        unsigned o1 = __builtin_amdgcn_perm(s2, s3, sel);
        unsigned row_ = (unsigned)(cg*4 + j);
        unsigned g_ = ((unsigned)rg) ^ (((row_ >> 2) & 3u) << 2);
        *(u32x2*)(&LT[row_*128u + g_*8u]) = (u32x2){o0, o1};
    }
    __syncthreads();
    int c = t >> 2, ch = t & 3;
    unsigned key16 = (((unsigned)c >> 2) & 3u) << 1;
    unsigned p0 = ((unsigned)(2*ch))     ^ key16;
    unsigned p1 = ((unsigned)(2*ch + 1)) ^ key16;
    u32x4 r0 = *(const u32x4*)(&LT[(unsigned)c*128u + p0*16u]);
    u32x4 r1 = *(const u32x4*)(&LT[(unsigned)c*128u + p1*16u]);
    unsigned short* dp = dst + (size_t)c*dld + ch*16;
    *(u32x4*)(dp)     = r0;
    *(u32x4*)(dp + 8) = r1;
}

// ---------------- gating (+fused x->f16 cast) ----------------
__global__ __launch_bounds__(256) void k_gating(
    const float* __restrict__ x, const float* __restrict__ pl,
    const float* __restrict__ Wt, const float* __restrict__ Wgt,
    const float* __restrict__ Wel, float* __restrict__ out,
    float* __restrict__ coef, int* __restrict__ cnt,
    unsigned short* __restrict__ x16)
{
    int t = blockIdx.x;
    const float* xt = x + (size_t)t * ND;
    float acc[NK] = {0,0,0,0,0,0,0,0};
    for (int d = threadIdx.x; d < ND; d += 256){
        float xv = xt[d];
        const float4* w = (const float4*)(Wt + (size_t)d * NK);
        float4 w0 = w[0], w1 = w[1];
        acc[0] += xv*w0.x; acc[1] += xv*w0.y; acc[2] += xv*w0.z; acc[3] += xv*w0.w;
        acc[4] += xv*w1.x; acc[5] += xv*w1.y; acc[6] += xv*w1.z; acc[7] += xv*w1.w;
    }
    {   // fused f16 cast of this token's row (L1-hot re-read, coalesced 8B stores)
        int i4 = threadIdx.x * 4;
        f32x4 xv = *(const f32x4*)(xt + i4);
        u32x2 o = {pkrtz(xv[0], xv[1]), pkrtz(xv[2], xv[3])};
        *(u32x2*)(x16 + (size_t)t*ND + i4) = o;
    }
    __shared__ float red[4][NK];
    #pragma unroll
    for (int k = 0; k < NK; k++){
        float v = acc[k];
        #pragma unroll
        for (int off = 32; off; off >>= 1) v += __shfl_down(v, off);
        if ((threadIdx.x & 63) == 0) red[threadIdx.x >> 6][k] = v;
    }
    __syncthreads();
    if (threadIdx.x == 0){
        const float* p = pl + (size_t)t * NK;
        float pv[NK];
        #pragma unroll
        for (int j = 0; j < NK; j++) pv[j] = p[j];
        float lg[NK]; float mx = -1e30f;
        #pragma unroll
        for (int k = 0; k < NK; k++){
            float v = red[0][k] + red[1][k] + red[2][k] + red[3][k];
            #pragma unroll
            for (int j = 0; j < NK; j++) v += pv[j] * Wgt[j*NK + k];
            lg[k] = v; mx = fmaxf(mx, v);
            out[LG_OFF + (size_t)t*NK + k] = v;
        }
        float e[NK]; float s = 0.f;
        #pragma unroll
        for (int k = 0; k < NK; k++){ e[k] = expf(lg[k] - mx); s += e[k]; }
        float g[NK]; float gsum = 0.f;
        #pragma unroll
        for (int k = 0; k < NK; k++){
            float st = e[k] / s;
            float we = 1.f / (1.f + expf(-Wel[k]));
            bool m = st > LAMBDA_C * we;
            g[k] = m ? st : 0.f;
            gsum += g[k];
        }
        float inv = 1.f / (gsum + 1e-6f);
        #pragma unroll
        for (int k = 0; k < NK; k++){
            coef[(size_t)t*NK + k] = g[k] * inv;
            if (g[k] > 0.f) atomicAdd(&cnt[k], 1);
        }
    }
}

// ---------------- scan ----------------
__global__ __launch_bounds__(256) void k_scan(
    const float* __restrict__ coef, int* __restrict__ wsi,
    float* __restrict__ wsf, int pair_cap)
{
    int k = blockIdx.x;
    const int* cnt = wsi + WS_CNT;
    int base = 0;
    for (int j = 0; j < k; j++) base += cnt[j];
    int tid = threadIdx.x, lane = tid & 63, w = tid >> 6;
    __shared__ int wsum[4];
    __shared__ int sbase;
    if (tid == 0){
        sbase = base;
        wsi[WS_SEG + k] = base;
        if (k == NK-1) wsi[WS_SEG + NK] = base + cnt[k];
    }
    __syncthreads();
    int* ptok = wsi + WS_PTOK;
    float* pc = wsf + WS_PCOEF;
    for (int c0 = 0; c0 < NTOK; c0 += 256){
        int t = c0 + tid;
        float c = coef[(size_t)t*NK + k];
        bool m = c > 0.f;
        unsigned long long bal = __ballot(m);
        int pre = __popcll(bal & ((1ull << lane) - 1ull));
        if (lane == 0) wsum[w] = __popcll(bal);
        __syncthreads();
        int b = sbase;
        for (int j = 0; j < w; j++) b += wsum[j];
        if (m){
            int pos = b + pre;
            if (pos < pair_cap){ ptok[pos] = t; pc[pos] = c; }
        }
        __syncthreads();
        if (tid == 0) sbase += wsum[0] + wsum[1] + wsum[2] + wsum[3];
        __syncthreads();
    }
}

// ---------------- tiles + small outputs ----------------
__global__ void k_tiles(int* __restrict__ wsi, float* __restrict__ out, int pair_cap)
{
    if (threadIdx.x == 0 && blockIdx.x == 0){
        const int* cnt = wsi + WS_CNT;
        const int* seg = wsi + WS_SEG;
        int total = 0;
        for (int k = 0; k < NK; k++){ total += cnt[k]; out[SC_OFF + k] = (float)cnt[k]; }
        out[AD_OFF] = (float)total / (float)NTOK;
        int nt = 0;
        for (int k = 0; k < NK; k++){
            int e = min(seg[k+1], pair_cap);
            for (int r = seg[k]; r < e; r += BM){
                wsi[WS_TILEK + nt] = k; wsi[WS_TILER + nt] = r; nt++;
            }
        }
        wsi[WS_NTILES] = nt;
    }
}

// XCD-chunked bijective work partition
#define XCD_PART_LOOP(nwork)                                              \
    int q_ = (nwork) >> 3, rr_ = (nwork) & 7;                             \
    int xcd_ = blockIdx.x & 7;                                            \
    int slot_ = blockIdx.x >> 3;                                          \
    int nslot_ = gridDim.x >> 3;                                          \
    int cntw_ = q_ + (xcd_ < rr_ ? 1 : 0);                                \
    int start_ = xcd_ * q_ + (xcd_ < rr_ ? xcd_ : rr_);                   \
    for (int p_ = slot_; p_ < cntw_; p_ += nslot_)

// ============== NEW-PATH m97-style GEMMs, 3-slot GLL pipeline ==============
#define GLLN(aP0_, aP1_, bP0_, bP1_, t_, slot_)                           \
  { unsigned ab_ = (unsigned)(slot_)*16384u + (unsigned)(wv*1024);        \
    __builtin_amdgcn_global_load_lds(                                     \
        (const __attribute__((address_space(1))) void*)((aP0_) + (size_t)(t_)*32), \
        (__attribute__((address_space(3))) void*)(&lds[ab_]), 16, 0, 0);  \
    __builtin_amdgcn_global_load_lds(                                     \
        (const __attribute__((address_space(1))) void*)((aP1_) + (size_t)(t_)*32), \
        (__attribute__((address_space(3))) void*)(&lds[ab_ + 4096u]), 16, 0, 0); \
    __builtin_amdgcn_global_load_lds(                                     \
        (const __attribute__((address_space(1))) void*)((bP0_) + (size_t)(t_)*32), \
        (__attribute__((address_space(3))) void*)(&lds[ab_ + 8192u]), 16, 0, 0); \
    __builtin_amdgcn_global_load_lds(                                     \
        (const __attribute__((address_space(1))) void*)((bP1_) + (size_t)(t_)*32), \
        (__attribute__((address_space(3))) void*)(&lds[ab_ + 12288u]), 16, 0, 0); }

#define MFMAN(slot_)                                                      \
  { unsigned ab_ = (unsigned)(slot_)*16384u, bb_ = ab_ + 8192u;           \
    f16x8 af_[4], bf_[4];                                                 \
    _Pragma("unroll")                                                     \
    for (int m_ = 0; m_ < 4; m_++) af_[m_] = *(const f16x8*)(&lds[ab_ + aoff[m_]]); \
    _Pragma("unroll")                                                     \
    for (int n_ = 0; n_ < 4; n_++) bf_[n_] = *(const f16x8*)(&lds[bb_ + boff[n_]]); \
    __builtin_amdgcn_s_setprio(1);                                        \
    _Pragma("unroll")                                                     \
    for (int m_ = 0; m_ < 4; m_++)                                        \
    _Pragma("unroll")                                                     \
    for (int n_ = 0; n_ < 4; n_++)                                        \
        acc[m_][n_] = __builtin_amdgcn_mfma_f32_16x16x32_f16(af_[m_], bf_[n_], acc[m_][n_], 0, 0, 0); \
    __builtin_amdgcn_s_setprio(0); }

#define PIPE_N(APREF0_, APREF1_, BPREF0_, BPREF1_)                        \
    GLLN(APREF0_, APREF1_, BPREF0_, BPREF1_, 0, 0)                        \
    GLLN(APREF0_, APREF1_, BPREF0_, BPREF1_, 1, 1)                        \
    asm volatile("s_waitcnt vmcnt(4)" ::: "memory");                      \
    __builtin_amdgcn_s_barrier();                                         \
    __builtin_amdgcn_sched_barrier(0);                                    \
    for (int t = 0; t < 32; t++){                                         \
        int sl = t % 3;                                                   \
        if (t + 2 < 32){                                                  \
            GLLN(APREF0_, APREF1_, BPREF0_, BPREF1_, t+2, (t+2)%3)        \
            MFMAN(sl)                                                     \
            asm volatile("s_waitcnt vmcnt(4)" ::: "memory");              \
            __builtin_amdgcn_s_barrier();                                 \
            __builtin_amdgcn_sched_barrier(0);                            \
        } else if (t + 1 < 32){                                           \
            MFMAN(sl)                                                     \
            asm volatile("s_waitcnt vmcnt(0)" ::: "memory");              \
            __builtin_amdgcn_s_barrier();                                 \
            __builtin_amdgcn_sched_barrier(0);                            \
        } else {                                                          \
            MFMAN(sl)                                                     \
        }                                                                 \
    }

#define GEMMN_PRE()                                                       \
    int tid = threadIdx.x;                                                \
    int L = tid & 63;                                                     \
    int wv = tid >> 6;                                                    \
    int wr = wv >> 1, wc = wv & 1;                                        \
    int l15 = L & 15, q = L >> 4;                                         \
    unsigned aoff[4], boff[4];                                            \
    _Pragma("unroll")                                                     \
    for (int m_ = 0; m_ < 4; m_++){                                       \
        int r_ = wr*64 + m_*16 + l15;                                     \
        aoff[m_] = (unsigned)(r_*64) + ((unsigned)((q ^ r_) & 3) << 4);   \
    }                                                                     \
    _Pragma("unroll")                                                     \
    for (int n_ = 0; n_ < 4; n_++){                                       \
        int c_ = wc*64 + n_*16 + l15;                                     \
        boff[n_] = (unsigned)(c_*64) + ((unsigned)((q ^ c_) & 3) << 4);   \
    }                                                                     \
    int grow0 = wv*16 + (L >> 2);                                         \
    int grow1 = (4 + wv)*16 + (L >> 2);                                   \
    int qg8 = (((L & 3) ^ ((L >> 2) & 3))) * 8;

__global__ __launch_bounds__(256, 3) void k_gemm1n(
    const unsigned short* __restrict__ x16, const unsigned short* __restrict__ w1t,
    const float* __restrict__ b1, const int* __restrict__ wsi,
    unsigned short* __restrict__ hbuf, int pair_cap)
{
    __shared__ char lds[49152];
    __shared__ int stok[BM];
    const int* seg  = wsi + WS_SEG;
    const int* tk   = wsi + WS_TILEK;
    const int* tr   = wsi + WS_TILER;
    const int* ptok = wsi + WS_PTOK;
    int ntm = wsi[WS_NTILES];
    int nwork = ntm * (NF / 128);
    GEMMN_PRE()

    XCD_PART_LOOP(nwork){
        int widx = start_ + p_;
        int mt = widx % ntm;
        int ft = widx / ntm;
        int kexp = tk[mt];
        int row0 = tr[mt];
        int nrows = min(BM, seg[kexp+1] - row0);
        int f0 = ft * 128;
        __syncthreads();
        if (tid < BM){
            int r = row0 + tid;
            stok[tid] = (tid < nrows && r < pair_cap) ? ptok[r] : ptok[row0];
        }
        __syncthreads();
        const unsigned short* a0 = x16 + (size_t)stok[grow0]*ND + qg8;
        const unsigned short* a1 = x16 + (size_t)stok[grow1]*ND + qg8;
        const unsigned short* bb = w1t + (size_t)kexp*NF*ND;
        const unsigned short* b0 = bb + (size_t)(f0 + grow0)*ND + qg8;
        const unsigned short* b1p = bb + (size_t)(f0 + grow1)*ND + qg8;
        f32x4 acc[4][4] = {};
        PIPE_N(a0, a1, b0, b1p)
        // epilogue: LDS-bounce -> coalesced 16B hbuf stores
        __syncthreads();
        const float* b1k = b1 + (size_t)kexp*NF;
        #pragma unroll
        for (int n = 0; n < 4; n++){
            int fl = wc*64 + n*16 + l15;
            float bv = b1k[f0 + fl];
            unsigned col2 = (unsigned)fl * 2u;
            #pragma unroll
            for (int m = 0; m < 4; m++){
                int rb = wr*64 + m*16 + q*4;
                #pragma unroll
                for (int i = 0; i < 4; i++){
                    int r = rb + i;
                    float v = gelu_exact(acc[m][n][i] + bv);
                    unsigned short hv = (unsigned short)(pkrtz(v, 0.f) & 0xffffu);
                    unsigned pp = (col2 >> 4) ^ ((unsigned)r & 15u);
                    *(unsigned short*)(&lds[(unsigned)r*256u + pp*16u + (col2 & 15u)]) = hv;
                }
            }
        }
        __syncthreads();
        {
            int r = tid >> 1, half = tid & 1;
            if (r < nrows && row0 + r < pair_cap){
                unsigned short* dp = hbuf + (size_t)(row0+r)*NF + f0 + half*64;
                #pragma unroll
                for (int j = 0; j < 8; j++){
                    unsigned pp = ((unsigned)(half*8 + j)) ^ ((unsigned)r & 15u);
                    *(u32x4*)(dp + j*8) = *(const u32x4*)(&lds[(unsigned)r*256u + pp*16u]);
                }
            }
        }
    }
}

__global__ __launch_bounds__(256, 3) void k_gemm2n(
    const unsigned short* __restrict__ hbuf, const unsigned short* __restrict__ w2t,
    const float* __restrict__ b2, const int* __restrict__ wsi,
    const float* __restrict__ wsf, float* __restrict__ out, int pair_cap)
{
    __shared__ char lds[49152];
    __shared__ int stok[BM];
    __shared__ float scoef[BM];
    const int* seg  = wsi + WS_SEG;
    const int* tk   = wsi + WS_TILEK;
    const int* tr   = wsi + WS_TILER;
    const int* ptok = wsi + WS_PTOK;
    const float* pcoef = wsf + WS_PCOEF;
    int ntm = wsi[WS_NTILES];
    int nwork = ntm * (ND / 128) * SPLITK2;
    GEMMN_PRE()

    XCD_PART_LOOP(nwork){
        int widx = start_ + p_;
        int mt = widx % ntm;
        int rest = widx / ntm;
        int dt = rest & 7;
        int spk = rest >> 3;
        int kexp = tk[mt];
        int row0 = tr[mt];
        int nrows = min(BM, seg[kexp+1] - row0);
        int d0 = dt * 128;
        __syncthreads();
        if (tid < BM){
            int r = row0 + tid;
            bool v = (tid < nrows && r < pair_cap);
            stok[tid]  = v ? ptok[r] : 0;
            scoef[tid] = v ? pcoef[r] : 0.f;
        }
        __syncthreads();
        int ar0 = row0 + grow0; if (ar0 >= pair_cap) ar0 = pair_cap - 1;
        int ar1 = row0 + grow1; if (ar1 >= pair_cap) ar1 = pair_cap - 1;
        const unsigned short* a0 = hbuf + (size_t)ar0*NF + spk*(NF/SPLITK2) + qg8;
        const unsigned short* a1 = hbuf + (size_t)ar1*NF + spk*(NF/SPLITK2) + qg8;
        const unsigned short* bb = w2t + (size_t)kexp*ND*NF + spk*(NF/SPLITK2);
        const unsigned short* b0 = bb + (size_t)(d0 + grow0)*NF + qg8;
        const unsigned short* b1p = bb + (size_t)(d0 + grow1)*NF + qg8;
        f32x4 acc[4][4] = {};
        PIPE_N(a0, a1, b0, b1p)
        const float* b2k = b2 + (size_t)kexp*ND;
        #pragma unroll
        for (int n = 0; n < 4; n++){
            int d = d0 + wc*64 + n*16 + l15;
            float bv = (spk == 0) ? b2k[d] : 0.f;
            #pragma unroll
            for (int m = 0; m < 4; m++){
                int rl = wr*64 + m*16 + q*4;
                #pragma unroll
                for (int i = 0; i < 4; i++){
                    int r = rl + i;
                    if (r < nrows && row0 + r < pair_cap){
                        float c = scoef[r];
                        atomicAdd(&out[(size_t)stok[r]*ND + d], c * (acc[m][n][i] + bv));
                    }
                }
            }
        }
    }
}

// ============== FALLBACK (R13) GEMMs ==============
#define LOAD_A(dst_, tt_)                                                 \
    { const unsigned short* an_ = asrc + (tt_)*BK;                        \
      _Pragma("unroll")                                                   \
      for (int j_ = 0; j_ < 4; j_++) dst_[j_] = *(const u32x4*)(an_ + j_*8); }

#define LOAD_B(dst_, tt_, LDW_)                                           \
    { const float* bn_ = bsrc + (size_t)((tt_)*BK + bkq*4)*LDW_;          \
      _Pragma("unroll")                                                   \
      for (int r_ = 0; r_ < 4; r_++) dst_[r_] = *(const f32x4*)(bn_ + (size_t)r_*LDW_); }

#define STAGE_A(src_, AO_)                                                \
    { _Pragma("unroll")                                                   \
      for (int j_ = 0; j_ < 4; j_++){                                     \
          unsigned off_ = (AO_) + (unsigned)arow*128u +                   \
              ((((unsigned)(ahalf*4 + j_)) ^ (unsigned)(arow & 7)) << 4); \
          *(u32x4*)(&lds[off_]) = src_[j_];                               \
      } }

#define STAGE_B(src_, BO_)                                                \
    { unsigned wA_[4], wB_[4];                                            \
      _Pragma("unroll")                                                   \
      for (int r_ = 0; r_ < 4; r_++){                                     \
          wA_[r_] = pkrtz(src_[r_][0], src_[r_][1]);                      \
          wB_[r_] = pkrtz(src_[r_][2], src_[r_][3]);                      \
      }                                                                   \
      _Pragma("unroll")                                                   \
      for (int j_ = 0; j_ < 4; j_++){                                     \
          unsigned s0_ = (j_ < 2) ? wA_[1] : wB_[1];                      \
          unsigned s1_ = (j_ < 2) ? wA_[0] : wB_[0];                      \
          unsigned s2_ = (j_ < 2) ? wA_[3] : wB_[3];                      \
          unsigned s3_ = (j_ < 2) ? wA_[2] : wB_[2];                      \
          unsigned sel_ = (j_ & 1) ? 0x07060302u : 0x05040100u;           \
          unsigned o0_ = __builtin_amdgcn_perm(s0_, s1_, sel_);           \
          unsigned o1_ = __builtin_amdgcn_perm(s2_, s3_, sel_);           \
          unsigned col_ = (unsigned)(bcc*4 + j_);                         \
          unsigned off_ = (BO_) + col_*128u +                             \
              (((unsigned)(bkq*8)) ^ ((col_ & 7u) << 4));                 \
          *(u32x2*)(&lds[off_]) = (u32x2){o0_, o1_};                      \
      } }

#define MFMA_RD(AO_, BO_)                                                 \
    { __builtin_amdgcn_s_setprio(1);                                      \
      _Pragma("unroll")                                                   \
      for (int kk_ = 0; kk_ < 2; kk_++){                                  \
          unsigned sb_ = ((unsigned)(kk_*64 + q*16)) ^ swzL;              \
          f16x8 af_[4], bf_[2];                                           \
          _Pragma("unroll")                                               \
          for (int m_ = 0; m_ < 4; m_++)                                  \
              af_[m_] = *(const f16x8*)(&lds[(AO_) + (unsigned)(wr*64 + m_*16 + l15)*128u + sb_]); \
          _Pragma("unroll")                                               \
          for (int n_ = 0; n_ < 2; n_++)                                  \
              bf_[n_] = *(const f16x8*)(&lds[(BO_) + (unsigned)(wc*32 + n_*16 + l15)*128u + sb_]); \
          _Pragma("unroll")                                               \
          for (int m_ = 0; m_ < 4; m_++)                                  \
          _Pragma("unroll")                                               \
          for (int n_ = 0; n_ < 2; n_++)                                  \
              acc[m_][n_] = __builtin_amdgcn_mfma_f32_16x16x32_f16(af_[m_], bf_[n_], acc[m_][n_], 0, 0, 0); \
      }                                                                   \
      __builtin_amdgcn_s_setprio(0); }

#define STEP_SYNC()                                                       \
    asm volatile("s_waitcnt lgkmcnt(0)" ::: "memory");                    \
    __builtin_amdgcn_s_barrier();                                         \
    __builtin_amdgcn_sched_barrier(0);

__global__ __launch_bounds__(256, 3) void k_gemm1f(
    const unsigned short* __restrict__ x16, const float* __restrict__ W1,
    const float* __restrict__ b1, const int* __restrict__ wsi,
    unsigned short* __restrict__ hbuf, int pair_cap)
{
    __shared__ char lds[49152];
    __shared__ int stok[BM];
    const int* seg  = wsi + WS_SEG;
    const int* tk   = wsi + WS_TILEK;
    const int* tr   = wsi + WS_TILER;
    const int* ptok = wsi + WS_PTOK;
    int ntm = wsi[WS_NTILES];
    int nwork = ntm * (NF / BN);
    int tid  = threadIdx.x;
    int lane = tid & 63;
    int w    = tid >> 6;
    int wr = w >> 1, wc = w & 1;
    int l15 = lane & 15, q = lane >> 4;
    unsigned swzL = (unsigned)((l15 & 7) << 4);
    int arow = tid >> 1, ahalf = tid & 1;
    int bkq = tid >> 4, bcc = tid & 15;

    XCD_PART_LOOP(nwork){
        int widx = start_ + p_;
        int mt = widx % ntm;
        int ft = widx / ntm;
        int kexp = tk[mt];
        int row0 = tr[mt];
        int nrows = min(BM, seg[kexp+1] - row0);
        int f0 = ft * BN;
        __syncthreads();
        if (tid < BM){
            int r = row0 + tid;
            stok[tid] = (tid < nrows && r < pair_cap) ? ptok[r] : ptok[row0];
        }
        __syncthreads();
        const unsigned short* asrc = x16 + (size_t)stok[arow]*ND + ahalf*32;
        const float* bsrc = W1 + (size_t)kexp*ND*NF + f0 + bcc*4;
        u32x4 ga0[4], ga1[4]; f32x4 gb0[4], gb1[4];
        LOAD_A(ga0, 0) LOAD_B(gb0, 0, NF)
        LOAD_A(ga1, 1) LOAD_B(gb1, 1, NF)
        f32x4 acc[4][2] = {};
        for (int t = 0; t < KT; t += 2){
            STAGE_A(ga0, AOFF0) STAGE_B(gb0, BOFF0)
            if (t + 2 < KT){ LOAD_A(ga0, t+2) LOAD_B(gb0, t+2, NF) }
            STEP_SYNC()
            MFMA_RD(AOFF0, BOFF0)
            STAGE_A(ga1, AOFF1) STAGE_B(gb1, BOFF1)
            if (t + 3 < KT){ LOAD_A(ga1, t+3) LOAD_B(gb1, t+3, NF) }
            STEP_SYNC()
            MFMA_RD(AOFF1, BOFF1)
        }
        const float* b1k = b1 + (size_t)kexp*NF;
        #pragma unroll
        for (int n = 0; n < 2; n++){
            int f = f0 + wc*32 + n*16 + l15;
            float bv = b1k[f];
            #pragma unroll
            for (int m = 0; m < 4; m++){
                int rl = wr*64 + m*16 + q*4;
                #pragma unroll
                for (int i = 0; i < 4; i++){
                    int r = rl + i;
                    if (r < nrows && row0 + r < pair_cap){
                        float v = gelu_exact(acc[m][n][i] + bv);
                        hbuf[(size_t)(row0+r)*NF + f] = (unsigned short)(pkrtz(v, 0.f) & 0xffffu);
                    }
                }
            }
        }
    }
}

__global__ __launch_bounds__(256, 3) void k_gemm2f(
    const unsigned short* __restrict__ hbuf, const float* __restrict__ W2,
    const float* __restrict__ b2, const int* __restrict__ wsi,
    const float* __restrict__ wsf, float* __restrict__ out, int pair_cap)
{
    __shared__ char lds[49152];
    __shared__ int stok[BM];
    __shared__ float scoef[BM];
    const int* seg  = wsi + WS_SEG;
    const int* tk   = wsi + WS_TILEK;
    const int* tr   = wsi + WS_TILER;
    const int* ptok = wsi + WS_PTOK;
    const float* pcoef = wsf + WS_PCOEF;
    int ntm = wsi[WS_NTILES];
    int nwork = ntm * (ND / BN) * SPLITK2;
    int tid  = threadIdx.x;
    int lane = tid & 63;
    int w    = tid >> 6;
    int wr = w >> 1, wc = w & 1;
    int l15 = lane & 15, q = lane >> 4;
    unsigned swzL = (unsigned)((l15 & 7) << 4);
    int arow = tid >> 1, ahalf = tid & 1;
    int bkq = tid >> 4, bcc = tid & 15;

    XCD_PART_LOOP(nwork){
        int widx = start_ + p_;
        int mt = widx % ntm;
        int rest = widx / ntm;
        int dt = rest & 15;
        int sp = rest >> 4;
        int kexp = tk[mt];
        int row0 = tr[mt];
        int nrows = min(BM, seg[kexp+1] - row0);
        int d0 = dt * BN;
        __syncthreads();
        if (tid < BM){
            int r = row0 + tid;
            bool v = (tid < nrows && r < pair_cap);
            stok[tid]  = v ? ptok[r] : 0;
            scoef[tid] = v ? pcoef[r] : 0.f;
        }
        __syncthreads();
        int hr = row0 + arow; if (hr >= pair_cap) hr = pair_cap - 1;
        const unsigned short* asrc = hbuf + (size_t)hr*NF + sp*(NF/SPLITK2) + ahalf*32;
        const float* bsrc = W2 + (size_t)kexp*NF*ND + (size_t)sp*(NF/SPLITK2)*ND + d0 + bcc*4;
        u32x4 ga0[4], ga1[4]; f32x4 gb0[4], gb1[4];
        LOAD_A(ga0, 0) LOAD_B(gb0, 0, ND)
        LOAD_A(ga1, 1) LOAD_B(gb1, 1, ND)
        f32x4 acc[4][2] = {};
        for (int t = 0; t < KT; t += 2){
            STAGE_A(ga0, AOFF0) STAGE_B(gb0, BOFF0)
            if (t + 2 < KT){ LOAD_A(ga0, t+2) LOAD_B(gb0, t+2, ND) }
            STEP_SYNC()
            MFMA_RD(AOFF0, BOFF0)
            STAGE_A(ga1, AOFF1) STAGE_B(gb1, BOFF1)
            if (t + 3 < KT){ LOAD_A(ga1, t+3) LOAD_B(gb1, t+3, ND) }
            STEP_SYNC()
            MFMA_RD(AOFF1, BOFF1)
        }
        const float* b2k = b2 + (size_t)kexp*ND;
        #pragma unroll
        for (int n = 0; n < 2; n++){
            int d = d0 + wc*32 + n*16 + l15;
            float bv = (sp == 0) ? b2k[d] : 0.f;
            #pragma unroll
            for (int m = 0; m < 4; m++){
                int rl = wr*64 + m*16 + q*4;
                #pragma unroll
                for (int i = 0; i < 4; i++){
                    int r = rl + i;
                    if (r < nrows && row0 + r < pair_cap){
                        float c = scoef[r];
                        atomicAdd(&out[(size_t)stok[r]*ND + d], c * (acc[m][n][i] + bv));
                    }
                }
            }
        }
    }
}

extern "C" void kernel_launch(void* const* d_in, const int* in_sizes, int n_in,
                              void* d_out, int out_size, void* d_ws, size_t ws_size,
                              hipStream_t stream)
{
    const float* x   = (const float*)d_in[0];
    const float* pl  = (const float*)d_in[1];
    const float* Wt  = (const float*)d_in[2];
    const float* Wgt = (const float*)d_in[3];
    const float* Wel = (const float*)d_in[4];
    const float* W1  = (const float*)d_in[5];
    const float* b1  = (const float*)d_in[6];
    const float* W2  = (const float*)d_in[7];
    const float* b2  = (const float*)d_in[8];
    float* out = (float*)d_out;
    int* wsi   = (int*)d_ws;
    float* wsf = (float*)d_ws;
    unsigned short* x16 = (unsigned short*)((char*)d_ws + B_X16);

    long long capn = ((long long)ws_size - (long long)B_HBUFN) / ((long long)NF*2);
    bool newpath = capn >= 4096;

    hipMemsetAsync(d_out, 0, (size_t)out_size*sizeof(float), stream);
    hipMemsetAsync(d_ws, 0, 32, stream);   // cnt[8]
    k_gating<<<NTOK, 256, 0, stream>>>(x, pl, Wt, Wgt, Wel, out, wsf + WS_COEF, wsi + WS_CNT, x16);

    if (newpath){
        unsigned short* w1t  = (unsigned short*)((char*)d_ws + B_W1T);
        unsigned short* w2t  = (unsigned short*)((char*)d_ws + B_W2T);
        unsigned short* hbuf = (unsigned short*)((char*)d_ws + B_HBUFN);
        int pair_cap = (int)((capn > 32768) ? 32768 : capn);
        k_wtrans<<<16384, 256, 0, stream>>>(W1, W2, w1t, w2t);
        k_scan<<<NK, 256, 0, stream>>>(wsf + WS_COEF, wsi, wsf, pair_cap);
        k_tiles<<<1, 64, 0, stream>>>(wsi, out, pair_cap);
        k_gemm1n<<<2048, 256, 0, stream>>>(x16, w1t, b1, wsi, hbuf, pair_cap);
        k_gemm2n<<<2048, 256, 0, stream>>>(hbuf, w2t, b2, wsi, wsf, out, pair_cap);
    } else {
        unsigned short* hbuf = (unsigned short*)((char*)d_ws + B_HBUFF);
        long long cap = ((long long)ws_size - (long long)B_HBUFF) / ((long long)NF*2);
        if (cap > (long long)NTOK*NK) cap = (long long)NTOK*NK;
        if (cap < 0) cap = 0;
        int pair_cap = (int)cap;
        if (pair_cap > 0){
            k_scan<<<NK, 256, 0, stream>>>(wsf + WS_COEF, wsi, wsf, pair_cap);
            k_tiles<<<1, 64, 0, stream>>>(wsi, out, pair_cap);
            k_gemm1f<<<2048, 256, 0, stream>>>(x16, W1, b1, wsi, hbuf, pair_cap);
            k_gemm2f<<<2048, 256, 0, stream>>>(hbuf, W2, b2, wsi, wsf, out, pair_cap);
        }
    }
}